// Round 2
// baseline (933.963 us; speedup 1.0000x reference)
//
#include <hip/hip_runtime.h>
#include <math.h>

#define N_NODES 50000
#define N_EDGES 400000
#define DIM 512
#define NLAYER 3
#define INNER 2048
#define BN_EPS 1e-5f
#define MPAD 50176   // N_NODES rounded up to 256 (BM) multiple

typedef unsigned short u16;
typedef unsigned int u32;

typedef __attribute__((ext_vector_type(8))) short bf16x8;
typedef __attribute__((ext_vector_type(4))) float f32x4;

__device__ __forceinline__ u16 f2bf(float f) {
  union { float f; u32 u; } v; v.f = f;
  u32 u = v.u;
  u32 r = (u + 0x7FFFu + ((u >> 16) & 1u)) >> 16;  // RNE
  return (u16)r;
}
__device__ __forceinline__ float bf2f(u16 h) {
  union { u32 u; float f; } v; v.u = ((u32)h) << 16; return v.f;
}

#define GLOAD_LDS16(g, l)                                                       \
  __builtin_amdgcn_global_load_lds(                                             \
      (const __attribute__((address_space(1))) u32*)(g),                        \
      (__attribute__((address_space(3))) u32*)(l), 16, 0, 0)

// ---------------- graph prep ----------------

__global__ void k_deg(const int* __restrict__ ei, int* __restrict__ deg) {
  int e = blockIdx.x * blockDim.x + threadIdx.x;
  if (e < N_EDGES) atomicAdd(&deg[ei[N_EDGES + e]], 1);
}

__global__ void k_dinv(const int* __restrict__ deg, float* __restrict__ dinv) {
  int i = blockIdx.x * blockDim.x + threadIdx.x;
  if (i < N_NODES) dinv[i] = rsqrtf((float)(deg[i] + 1));
}

// parallel 3-phase scan
__global__ __launch_bounds__(1024) void k_scan1(const int* __restrict__ deg,
                                                int* __restrict__ bsum, int n) {
  __shared__ int wsum[16];
  int tid = threadIdx.x;
  int lane = tid & 63, wv = tid >> 6;
  int i = blockIdx.x * 1024 + tid;
  int x = (i < n) ? deg[i] : 0;
#pragma unroll
  for (int d = 1; d < 64; d <<= 1) x += __shfl_xor(x, d, 64);
  if (lane == 0) wsum[wv] = x;
  __syncthreads();
  if (tid == 0) {
    int s = 0;
#pragma unroll
    for (int k = 0; k < 16; k++) s += wsum[k];
    bsum[blockIdx.x] = s;
  }
}

__global__ void k_scan2(int* __restrict__ bsum, int* __restrict__ offs, int nb) {
  int lane = threadIdx.x;  // 64 threads, nb <= 64
  int v = (lane < nb) ? bsum[lane] : 0;
  int x = v;
#pragma unroll
  for (int d = 1; d < 64; d <<= 1) {
    int y = __shfl_up(x, d, 64);
    if (lane >= d) x += y;
  }
  if (lane < nb) bsum[lane] = x - v;  // exclusive base per block
  if (lane == nb - 1) offs[N_NODES] = x;  // grand total
}

__global__ __launch_bounds__(1024) void k_scan3(const int* __restrict__ deg,
                                                const int* __restrict__ bsum,
                                                int* __restrict__ offs, int n) {
  __shared__ int wsum[16];
  int tid = threadIdx.x;
  int lane = tid & 63, wv = tid >> 6;
  int i = blockIdx.x * 1024 + tid;
  int v = (i < n) ? deg[i] : 0;
  int x = v;
#pragma unroll
  for (int d = 1; d < 64; d <<= 1) {
    int y = __shfl_up(x, d, 64);
    if (lane >= d) x += y;
  }
  if (lane == 63) wsum[wv] = x;
  __syncthreads();
  if (wv == 0) {
    int w = (lane < 16) ? wsum[lane] : 0;
#pragma unroll
    for (int d = 1; d < 16; d <<= 1) {
      int y = __shfl_up(w, d, 64);
      if (lane >= d) w += y;
    }
    if (lane < 16) wsum[lane] = w;
  }
  __syncthreads();
  if (i < n) offs[i] = bsum[blockIdx.x] + (wv ? wsum[wv - 1] : 0) + x - v;
}

__global__ void k_fill(const int* __restrict__ ei, const int* __restrict__ offs,
                       int* __restrict__ cursor, const float* __restrict__ dinv,
                       int* __restrict__ csr_src, float* __restrict__ csr_norm) {
  int e = blockIdx.x * blockDim.x + threadIdx.x;
  if (e >= N_EDGES) return;
  int s = ei[e];
  int d = ei[N_EDGES + e];
  int p = atomicAdd(&cursor[d], 1);
  int idx = offs[d] + p;
  csr_src[idx] = s;
  csr_norm[idx] = dinv[s] * dinv[d];
}

// fp32 x -> bf16 into xcat column slice 0 (row stride INNER)
__global__ void k_convert(const float* __restrict__ src, u16* __restrict__ xcat, int n4) {
  int i = blockIdx.x * blockDim.x + threadIdx.x;
  if (i >= n4) return;
  float4 v = ((const float4*)src)[i];
  uint2 o;
  o.x = (u32)f2bf(v.x) | ((u32)f2bf(v.y) << 16);
  o.y = (u32)f2bf(v.z) | ((u32)f2bf(v.w) << 16);
  int row = i >> 7;            // DIM/4 = 128 chunks per row
  int c4 = (i & 127) * 4;
  *(uint2*)(xcat + (size_t)row * INNER + c4) = o;
}

// LDS-tiled transpose: W [K,512] fp32 -> WT [512,K] bf16, optional per-k scale.
__global__ __launch_bounds__(256) void k_transpose_tiled(
    const float* __restrict__ W, const float* __restrict__ scale,
    u16* __restrict__ WT, int K) {
  __shared__ float tile[32][33];
  int k0 = blockIdx.x * 32, j0 = blockIdx.y * 32;
  int c = threadIdx.x & 31, r8 = threadIdx.x >> 5;  // 8 rows per pass
#pragma unroll
  for (int rr = 0; rr < 4; rr++) {
    int row = rr * 8 + r8;
    float v = W[(size_t)(k0 + row) * DIM + j0 + c];
    if (scale) v *= scale[k0 + row];
    tile[row][c] = v;
  }
  __syncthreads();
#pragma unroll
  for (int rr = 0; rr < 4; rr++) {
    int row = rr * 8 + r8;
    WT[(size_t)(j0 + row) * K + k0 + c] = f2bf(tile[c][row]);
  }
}

// ---------------- GEMM: C[M,512] = A[M,K](lda) @ Bt[512,K]^T, bf16 in
// 256x256 tile, 8 waves (2M x 4N), per-wave output 128x64, BK=64.
// LDS layout per operand: [2 dbuf][2 ksub][256 rows][32 u16] -> every
// ds_read_b128 fragment read tiles a contiguous 1KB (conflict-free); the
// ksub-plane split is applied on the global SOURCE side of global_load_lds
// (linear LDS dest, rule #21). Tile-granularity prefetch 2-deep with counted
// vmcnt(8): next tile's 8 staging loads stay in flight across both barriers.
#define BM 256
#define BN 256
#define BK 64

// STAGE: stage K-tile t into buffer d. Per wave: rows [w*32,w*32+32) of both
// A and B tiles, both ksub planes = 8 x global_load_lds (1KB each).
#define STAGE2(t, d)                                                        \
  {                                                                         \
    const u16* a_ = aw + (size_t)(t) * 64;                                  \
    const u16* b_ = bw + (size_t)(t) * 64;                                  \
    u16* al = aL + (d) * 16384;                                             \
    u16* bl = bL + (d) * 16384;                                             \
    GLOAD_LDS16(a_, al);                                                    \
    GLOAD_LDS16(a_ + (size_t)16 * lda, al + 512);                           \
    GLOAD_LDS16(a_ + 32, al + 8192);                                        \
    GLOAD_LDS16(a_ + (size_t)16 * lda + 32, al + 8192 + 512);               \
    GLOAD_LDS16(b_, bl);                                                    \
    GLOAD_LDS16(b_ + (size_t)16 * K, bl + 512);                             \
    GLOAD_LDS16(b_ + 32, bl + 8192);                                        \
    GLOAD_LDS16(b_ + (size_t)16 * K + 32, bl + 8192 + 512);                 \
  }

// TILE_COMPUTE: 24 ds_read_b128 + 128 MFMA in two setprio clusters.
#define TILE_COMPUTE(d)                                                     \
  {                                                                         \
    const u16* ab = arp + (d) * 16384;                                      \
    const u16* bb = brp + (d) * 16384;                                      \
    bf16x8 af[4][2], bfr[4][2];                                             \
    _Pragma("unroll") for (int ii = 0; ii < 4; ii++)                        \
      _Pragma("unroll") for (int s = 0; s < 2; s++)                         \
        af[ii][s] = *(const bf16x8*)(ab + s * 8192 + ii * 512);             \
    _Pragma("unroll") for (int j = 0; j < 4; j++)                           \
      _Pragma("unroll") for (int s = 0; s < 2; s++)                         \
        bfr[j][s] = *(const bf16x8*)(bb + s * 8192 + j * 512);              \
    __builtin_amdgcn_s_setprio(1);                                          \
    _Pragma("unroll") for (int ii = 0; ii < 4; ii++)                        \
      _Pragma("unroll") for (int j = 0; j < 4; j++)                         \
        _Pragma("unroll") for (int s = 0; s < 2; s++)                       \
          acc[ii][j] = __builtin_amdgcn_mfma_f32_16x16x32_bf16(             \
              af[ii][s], bfr[j][s], acc[ii][j], 0, 0, 0);                   \
    __builtin_amdgcn_s_setprio(0);                                          \
    _Pragma("unroll") for (int ii = 0; ii < 4; ii++)                        \
      _Pragma("unroll") for (int s = 0; s < 2; s++)                         \
        af[ii][s] = *(const bf16x8*)(ab + s * 8192 + (4 + ii) * 512);       \
    __builtin_amdgcn_s_setprio(1);                                          \
    _Pragma("unroll") for (int ii = 0; ii < 4; ii++)                        \
      _Pragma("unroll") for (int j = 0; j < 4; j++)                         \
        _Pragma("unroll") for (int s = 0; s < 2; s++)                       \
          acc[4 + ii][j] = __builtin_amdgcn_mfma_f32_16x16x32_bf16(         \
              af[ii][s], bfr[j][s], acc[4 + ii][j], 0, 0, 0);               \
    __builtin_amdgcn_s_setprio(0);                                          \
  }

__global__ __launch_bounds__(512, 2) void gemm_bt(
    const u16* __restrict__ A, int lda,
    const u16* __restrict__ Bt, const float* __restrict__ bias,
    float* __restrict__ Cf, u16* __restrict__ Cb, int M, int K) {
  // index(d,s,row,col) = d*16384 + s*8192 + row*32 + col (u16)
  __shared__ __align__(16) u16 As_[2 * 2 * 256 * 32];  // 64 KB
  __shared__ __align__(16) u16 Bs_[2 * 2 * 256 * 32];  // 64 KB
  int tid = threadIdx.x;
  int w = tid >> 6, lane = tid & 63;
  int wr = w >> 2, wc = w & 3;

  // bijective XCD swizzle (grid = 392 = 8*49); pairs (nb=0,1) of one m-panel
  // land adjacent on the same XCD -> A-panel L2 reuse.
  int nwg = gridDim.x;
  int flat = blockIdx.x;
  int swz = flat;
  if ((nwg & 7) == 0) swz = (flat & 7) * (nwg >> 3) + (flat >> 3);
  int mb = swz >> 1, nb = swz & 1;
  int m0 = mb * BM, n0 = nb * BN;

  // staging source (per lane): 16 rows x 64B per gload; sr=row-in-chunk, sc=col
  int sr = lane >> 2;
  int sc = (lane & 3) * 8;
  const u16* aw = A + (size_t)(m0 + w * 32 + sr) * lda + sc;
  const u16* bw = Bt + (size_t)(n0 + w * 32 + sr) * K + sc;
  u16* aL = &As_[(size_t)(w * 32) * 32];  // d=0, s=0, wave rows base
  u16* bL = &Bs_[(size_t)(w * 32) * 32];

  // fragment read bases: A rows wr*128.., B rows wc*64..
  int lr16 = lane & 15, lq4 = lane >> 4;
  const u16* arp = &As_[(size_t)(wr * 128 + lr16) * 32 + lq4 * 8];
  const u16* brp = &Bs_[(size_t)(wc * 64 + lr16) * 32 + lq4 * 8];

  f32x4 acc[8][4];
#pragma unroll
  for (int i = 0; i < 8; i++)
#pragma unroll
    for (int j = 0; j < 4; j++) acc[i][j] = (f32x4){0.f, 0.f, 0.f, 0.f};

  STAGE2(0, 0);
  STAGE2(1, 1);

  int NT = K >> 6;  // K/BK: 8 (layers) or 32 (final)
  for (int t = 0; t < NT - 1; ++t) {
    asm volatile("s_waitcnt vmcnt(8)" ::: "memory");  // tile t landed; t+1 flying
    __builtin_amdgcn_s_barrier();
    TILE_COMPUTE(t & 1);
    __builtin_amdgcn_s_barrier();  // all waves done reading buf (t&1)
    if (t + 2 < NT) STAGE2(t + 2, t & 1);
  }
  asm volatile("s_waitcnt vmcnt(0)" ::: "memory");
  __builtin_amdgcn_s_barrier();
  TILE_COMPUTE((NT - 1) & 1);

  // epilogue: D[row][col], col = lane&15, row = (lane>>4)*4 + reg
#pragma unroll
  for (int i = 0; i < 8; i++) {
    int row_b = m0 + wr * 128 + i * 16 + lq4 * 4;
#pragma unroll
    for (int j = 0; j < 4; j++) {
      int col = n0 + wc * 64 + j * 16 + lr16;
      if (Cf) {
        float bv = bias ? bias[col] : 0.f;
#pragma unroll
        for (int r2 = 0; r2 < 4; r2++) {
          int row = row_b + r2;
          if (row < M) Cf[(size_t)row * DIM + col] = acc[i][j][r2] + bv;
        }
      } else {
        // bf16 scratch has MPAD rows: no bound check needed
#pragma unroll
        for (int r2 = 0; r2 < 4; r2++)
          Cb[(size_t)(row_b + r2) * DIM + col] = f2bf(acc[i][j][r2]);
      }
    }
  }
}

// ---------------- aggregation: one wave per node, 16B/lane, 4-deep edge pipeline
__device__ __forceinline__ void accum8(float* a, uint4 h, float w) {
  a[0] += w * bf2f((u16)(h.x & 0xffffu));
  a[1] += w * bf2f((u16)(h.x >> 16));
  a[2] += w * bf2f((u16)(h.y & 0xffffu));
  a[3] += w * bf2f((u16)(h.y >> 16));
  a[4] += w * bf2f((u16)(h.z & 0xffffu));
  a[5] += w * bf2f((u16)(h.z >> 16));
  a[6] += w * bf2f((u16)(h.w & 0xffffu));
  a[7] += w * bf2f((u16)(h.w >> 16));
}

// reads hp [*,DIM] dense; writes GELU(agg)+bias into xcat column slice (stride INNER)
__global__ __launch_bounds__(256) void k_aggregate(
    const u16* __restrict__ hp, const int* __restrict__ offs,
    const int* __restrict__ csr_src, const float* __restrict__ csr_norm,
    const float* __restrict__ dinv, const float* __restrict__ b,
    u16* __restrict__ out_slice) {
  int v = blockIdx.x * 4 + (threadIdx.x >> 6);
  if (v >= N_NODES) return;
  int lane = threadIdx.x & 63;
  int c8 = lane * 8;  // 8 bf16 = 16 B per lane; wave covers the full 1KB row
  float acc[8];
#pragma unroll
  for (int i = 0; i < 8; i++) acc[i] = 0.f;

  int e0 = offs[v], e1 = offs[v + 1];
  int e = e0;
  for (; e + 4 <= e1; e += 4) {
    int s0 = csr_src[e], s1 = csr_src[e + 1], s2 = csr_src[e + 2], s3 = csr_src[e + 3];
    float w0 = csr_norm[e], w1 = csr_norm[e + 1], w2 = csr_norm[e + 2], w3 = csr_norm[e + 3];
    uint4 h0 = *(const uint4*)(hp + (size_t)s0 * DIM + c8);
    uint4 h1 = *(const uint4*)(hp + (size_t)s1 * DIM + c8);
    uint4 h2 = *(const uint4*)(hp + (size_t)s2 * DIM + c8);
    uint4 h3 = *(const uint4*)(hp + (size_t)s3 * DIM + c8);
    accum8(acc, h0, w0);
    accum8(acc, h1, w1);
    accum8(acc, h2, w2);
    accum8(acc, h3, w3);
  }
  for (; e < e1; e++) {
    int s = csr_src[e];
    float w = csr_norm[e];
    uint4 hv = *(const uint4*)(hp + (size_t)s * DIM + c8);
    accum8(acc, hv, w);
  }
  float di = dinv[v];
  uint4 hv = *(const uint4*)(hp + (size_t)v * DIM + c8);
  accum8(acc, hv, di * di);
  const float4* bb = (const float4*)(b + c8);
  float4 b0 = bb[0], b1 = bb[1];
  acc[0] += b0.x; acc[1] += b0.y; acc[2] += b0.z; acc[3] += b0.w;
  acc[4] += b1.x; acc[5] += b1.y; acc[6] += b1.z; acc[7] += b1.w;
#pragma unroll
  for (int i = 0; i < 8; i++)
    acc[i] = 0.5f * acc[i] * (1.f + erff(acc[i] * 0.70710678118654752f));
  uint4 o;
  o.x = (u32)f2bf(acc[0]) | ((u32)f2bf(acc[1]) << 16);
  o.y = (u32)f2bf(acc[2]) | ((u32)f2bf(acc[3]) << 16);
  o.z = (u32)f2bf(acc[4]) | ((u32)f2bf(acc[5]) << 16);
  o.w = (u32)f2bf(acc[6]) | ((u32)f2bf(acc[7]) << 16);
  *(uint4*)(out_slice + (size_t)v * INNER + c8) = o;
}

// ---------------- BN stats over xcat [N_NODES, INNER] ----------------
__global__ void k_bn_stats(const u16* __restrict__ xcat,
                           float* __restrict__ sums, float* __restrict__ sumsq,
                           int rows_per) {
  int c = blockIdx.x * 512 + threadIdx.x * 2;  // column pair
  int r0 = blockIdx.y * rows_per;
  int r1 = min(N_NODES, r0 + rows_per);
  float s0 = 0.f, ss0 = 0.f, s1 = 0.f, ss1 = 0.f;
  for (int r = r0; r < r1; r++) {
    u32 u = *(const u32*)(xcat + (size_t)r * INNER + c);
    float x0 = bf2f((u16)(u & 0xffffu));
    float x1 = bf2f((u16)(u >> 16));
    s0 += x0; ss0 += x0 * x0;
    s1 += x1; ss1 += x1 * x1;
  }
  atomicAdd(&sums[c], s0);
  atomicAdd(&sumsq[c], ss0);
  atomicAdd(&sums[c + 1], s1);
  atomicAdd(&sumsq[c + 1], ss1);
}

__global__ void k_bn_finalize(const float* __restrict__ sums, const float* __restrict__ sumsq,
                              const float* __restrict__ gamma, const float* __restrict__ beta,
                              float* __restrict__ scale, float* __restrict__ shift) {
  int c = blockIdx.x * blockDim.x + threadIdx.x;
  if (c >= INNER) return;
  float mean = sums[c] / (float)N_NODES;
  float var = sumsq[c] / (float)N_NODES - mean * mean;
  float rstd = rsqrtf(var + BN_EPS);
  float sc = gamma[c] * rstd;
  scale[c] = sc;
  shift[c] = beta[c] - mean * sc;
}

// biasp (zero-initialized) += sum_k shift[k]*outW[k][:]; block 0 also adds outb
__global__ __launch_bounds__(256) void k_fold_bias(
    const float* __restrict__ outW, const float* __restrict__ shift,
    const float* __restrict__ outb, float* __restrict__ biasp) {
  int r0 = blockIdx.x * 64;  // 32 blocks x 64 rows
  int c = threadIdx.x * 2;
  float s0 = 0.f, s1 = 0.f;
  for (int r = 0; r < 64; r++) {
    int row = r0 + r;
    float sh = shift[row];
    float2 w = *(const float2*)(outW + (size_t)row * DIM + c);
    s0 += sh * w.x;
    s1 += sh * w.y;
  }
  if (blockIdx.x == 0) { s0 += outb[c]; s1 += outb[c + 1]; }
  atomicAdd(&biasp[c], s0);
  atomicAdd(&biasp[c + 1], s1);
}

// ---------------- launch ----------------
extern "C" void kernel_launch(void* const* d_in, const int* in_sizes, int n_in,
                              void* d_out, int out_size, void* d_ws, size_t ws_size,
                              hipStream_t stream) {
  (void)in_sizes; (void)n_in; (void)out_size; (void)ws_size;
  const float* x     = (const float*)d_in[0];
  const int*   ei    = (const int*)d_in[1];
  const float* Ws    = (const float*)d_in[2];
  const float* bs    = (const float*)d_in[3];
  const float* gamma = (const float*)d_in[4];
  const float* beta  = (const float*)d_in[5];
  const float* outW  = (const float*)d_in[6];
  const float* outb  = (const float*)d_in[7];
  float* out = (float*)d_out;
  u16*   hp  = (u16*)d_out;  // bf16 h scratch lives in d_out until the final GEMM

  char* ws = (char*)d_ws;
  size_t off = 0;
  auto alloc = [&](size_t bytes) -> void* {
    void* p = ws + off;
    off = (off + bytes + 255) & ~(size_t)255;
    return p;
  };
  // zeroed region first (single memset)
  int*   deg    = (int*)alloc(N_NODES * 4);
  int*   cursor = (int*)alloc(N_NODES * 4);
  float* sums   = (float*)alloc(INNER * 4);
  float* sumsq  = (float*)alloc(INNER * 4);
  float* biasp  = (float*)alloc(DIM * 4);
  size_t zero_bytes = off;
  float* dinv     = (float*)alloc(N_NODES * 4);
  int*   offs     = (int*)alloc((N_NODES + 1) * 4);
  int*   bsum     = (int*)alloc(64 * 4);
  int*   csr_src  = (int*)alloc(N_EDGES * 4);
  float* csr_norm = (float*)alloc(N_EDGES * 4);
  u16*   xcat = (u16*)alloc((size_t)MPAD * INNER * 2);  // unified concat [MPAD, 2048]
  u16*   WbT  = (u16*)alloc((size_t)DIM * DIM * 2);
  u16*   WpT  = (u16*)alloc((size_t)INNER * DIM * 2);
  float* scale = (float*)alloc(INNER * 4);
  float* shift = (float*)alloc(INNER * 4);

  const int SCAN_BLOCKS = (N_NODES + 1023) / 1024;  // 49

  hipMemsetAsync(d_ws, 0, zero_bytes, stream);
  k_deg<<<(N_EDGES + 255) / 256, 256, 0, stream>>>(ei, deg);
  k_dinv<<<(N_NODES + 255) / 256, 256, 0, stream>>>(deg, dinv);
  k_scan1<<<SCAN_BLOCKS, 1024, 0, stream>>>(deg, bsum, N_NODES);
  k_scan2<<<1, 64, 0, stream>>>(bsum, offs, SCAN_BLOCKS);
  k_scan3<<<SCAN_BLOCKS, 1024, 0, stream>>>(deg, bsum, offs, N_NODES);
  k_fill<<<(N_EDGES + 255) / 256, 256, 0, stream>>>(ei, offs, cursor, dinv, csr_src, csr_norm);
  k_convert<<<((N_NODES * DIM / 4) + 255) / 256, 256, 0, stream>>>(x, xcat, N_NODES * DIM / 4);

  dim3 ggrid((MPAD / BM) * (DIM / BN));  // 196*2 = 392 = 8*49 (XCD-divisible)
  for (int l = 0; l < NLAYER; l++) {
    k_transpose_tiled<<<dim3(DIM / 32, DIM / 32), 256, 0, stream>>>(
        Ws + (size_t)l * DIM * DIM, nullptr, WbT, DIM);
    gemm_bt<<<ggrid, 512, 0, stream>>>(xcat + (size_t)l * DIM, INNER, WbT, nullptr,
                                       nullptr, hp, N_NODES, DIM);
    k_aggregate<<<(N_NODES + 3) / 4, 256, 0, stream>>>(hp, offs, csr_src, csr_norm, dinv,
                                                       bs + (size_t)l * DIM,
                                                       xcat + (size_t)(l + 1) * DIM);
  }
  k_bn_stats<<<dim3(INNER / 512, 125), 256, 0, stream>>>(xcat, sums, sumsq, 400);
  k_bn_finalize<<<INNER / 256, 256, 0, stream>>>(sums, sumsq, gamma, beta, scale, shift);
  k_transpose_tiled<<<dim3(INNER / 32, DIM / 32), 256, 0, stream>>>(outW, scale, WpT, INNER);
  k_fold_bias<<<INNER / 64, 256, 0, stream>>>(outW, shift, outb, biasp);
  gemm_bt<<<ggrid, 512, 0, stream>>>(xcat, INNER, WpT, biasp,
                                     out, nullptr, N_NODES, INNER);
}

// Round 3
// 878.277 us; speedup vs baseline: 1.0634x; 1.0634x over previous
//
#include <hip/hip_runtime.h>
#include <math.h>

#define N_NODES 50000
#define N_EDGES 400000
#define DIM 512
#define NLAYER 3
#define INNER 2048
#define BN_EPS 1e-5f
#define MPAD 50176   // N_NODES rounded up to 256 (BM) multiple

typedef unsigned short u16;
typedef unsigned int u32;

typedef __attribute__((ext_vector_type(8))) short bf16x8;
typedef __attribute__((ext_vector_type(4))) float f32x4;

__device__ __forceinline__ u16 f2bf(float f) {
  union { float f; u32 u; } v; v.f = f;
  u32 u = v.u;
  u32 r = (u + 0x7FFFu + ((u >> 16) & 1u)) >> 16;  // RNE
  return (u16)r;
}
__device__ __forceinline__ float bf2f(u16 h) {
  union { u32 u; float f; } v; v.u = ((u32)h) << 16; return v.f;
}

#define GLOAD_LDS16(g, l)                                                       \
  __builtin_amdgcn_global_load_lds(                                             \
      (const __attribute__((address_space(1))) u32*)(g),                        \
      (__attribute__((address_space(3))) u32*)(l), 16, 0, 0)

// ---------------- graph prep ----------------

__global__ void k_deg(const int* __restrict__ ei, int* __restrict__ deg) {
  int e = blockIdx.x * blockDim.x + threadIdx.x;
  if (e < N_EDGES) atomicAdd(&deg[ei[N_EDGES + e]], 1);
}

__global__ void k_dinv(const int* __restrict__ deg, float* __restrict__ dinv) {
  int i = blockIdx.x * blockDim.x + threadIdx.x;
  if (i < N_NODES) dinv[i] = rsqrtf((float)(deg[i] + 1));
}

// parallel 3-phase scan
__global__ __launch_bounds__(1024) void k_scan1(const int* __restrict__ deg,
                                                int* __restrict__ bsum, int n) {
  __shared__ int wsum[16];
  int tid = threadIdx.x;
  int lane = tid & 63, wv = tid >> 6;
  int i = blockIdx.x * 1024 + tid;
  int x = (i < n) ? deg[i] : 0;
#pragma unroll
  for (int d = 1; d < 64; d <<= 1) x += __shfl_xor(x, d, 64);
  if (lane == 0) wsum[wv] = x;
  __syncthreads();
  if (tid == 0) {
    int s = 0;
#pragma unroll
    for (int k = 0; k < 16; k++) s += wsum[k];
    bsum[blockIdx.x] = s;
  }
}

__global__ void k_scan2(int* __restrict__ bsum, int* __restrict__ offs, int nb) {
  int lane = threadIdx.x;  // 64 threads, nb <= 64
  int v = (lane < nb) ? bsum[lane] : 0;
  int x = v;
#pragma unroll
  for (int d = 1; d < 64; d <<= 1) {
    int y = __shfl_up(x, d, 64);
    if (lane >= d) x += y;
  }
  if (lane < nb) bsum[lane] = x - v;  // exclusive base per block
  if (lane == nb - 1) offs[N_NODES] = x;  // grand total
}

__global__ __launch_bounds__(1024) void k_scan3(const int* __restrict__ deg,
                                                const int* __restrict__ bsum,
                                                int* __restrict__ offs, int n) {
  __shared__ int wsum[16];
  int tid = threadIdx.x;
  int lane = tid & 63, wv = tid >> 6;
  int i = blockIdx.x * 1024 + tid;
  int v = (i < n) ? deg[i] : 0;
  int x = v;
#pragma unroll
  for (int d = 1; d < 64; d <<= 1) {
    int y = __shfl_up(x, d, 64);
    if (lane >= d) x += y;
  }
  if (lane == 63) wsum[wv] = x;
  __syncthreads();
  if (wv == 0) {
    int w = (lane < 16) ? wsum[lane] : 0;
#pragma unroll
    for (int d = 1; d < 16; d <<= 1) {
      int y = __shfl_up(w, d, 64);
      if (lane >= d) w += y;
    }
    if (lane < 16) wsum[lane] = w;
  }
  __syncthreads();
  if (i < n) offs[i] = bsum[blockIdx.x] + (wv ? wsum[wv - 1] : 0) + x - v;
}

__global__ void k_fill(const int* __restrict__ ei, const int* __restrict__ offs,
                       int* __restrict__ cursor, const float* __restrict__ dinv,
                       int* __restrict__ csr_src, float* __restrict__ csr_norm) {
  int e = blockIdx.x * blockDim.x + threadIdx.x;
  if (e >= N_EDGES) return;
  int s = ei[e];
  int d = ei[N_EDGES + e];
  int p = atomicAdd(&cursor[d], 1);
  int idx = offs[d] + p;
  csr_src[idx] = s;
  csr_norm[idx] = dinv[s] * dinv[d];
}

// fp32 x -> bf16 into xcat column slice 0 (row stride INNER)
__global__ void k_convert(const float* __restrict__ src, u16* __restrict__ xcat, int n4) {
  int i = blockIdx.x * blockDim.x + threadIdx.x;
  if (i >= n4) return;
  float4 v = ((const float4*)src)[i];
  uint2 o;
  o.x = (u32)f2bf(v.x) | ((u32)f2bf(v.y) << 16);
  o.y = (u32)f2bf(v.z) | ((u32)f2bf(v.w) << 16);
  int row = i >> 7;            // DIM/4 = 128 chunks per row
  int c4 = (i & 127) * 4;
  *(uint2*)(xcat + (size_t)row * INNER + c4) = o;
}

// LDS-tiled transpose: W [K,512] fp32 -> WT [512,K] bf16, optional per-k scale.
__global__ __launch_bounds__(256) void k_transpose_tiled(
    const float* __restrict__ W, const float* __restrict__ scale,
    u16* __restrict__ WT, int K) {
  __shared__ float tile[32][33];
  int k0 = blockIdx.x * 32, j0 = blockIdx.y * 32;
  int c = threadIdx.x & 31, r8 = threadIdx.x >> 5;  // 8 rows per pass
#pragma unroll
  for (int rr = 0; rr < 4; rr++) {
    int row = rr * 8 + r8;
    float v = W[(size_t)(k0 + row) * DIM + j0 + c];
    if (scale) v *= scale[k0 + row];
    tile[row][c] = v;
  }
  __syncthreads();
#pragma unroll
  for (int rr = 0; rr < 4; rr++) {
    int row = rr * 8 + r8;
    WT[(size_t)(j0 + row) * K + k0 + c] = f2bf(tile[c][row]);
  }
}

// ---------------- GEMM: C[M,512] = A[M,K](lda) @ Bt[512,K]^T, bf16 in
// 256x256 tile, 8 waves (2M x 4N), BK=64, 4-phase fine interleave (T3+T4+T5).
// Phase p=(mh,nh) computes a 2x2 quadrant (16 MFMA), reads only its LDS chunk,
// and stages exactly one chunk (2 block-wide gloads) of tile t+1 into the
// other buffer. LDS chunks are binned by CONSUMING phase so every vmcnt wait
// is a counted vmcnt(4) -- never 0 in the main loop. Per-thread gload issue
// order per tile: A0, B0, B1, A1 (consumption order of the NEXT tile).
//   A LDS: [2 dbuf][2 mh][2 half=wr][2 ksub][64 r][32 c] u16  (64 KB)
//   B LDS: [2 dbuf][2 nh][2 wcg][2 ksub][64 r][32 c] u16      (64 KB)
// Every ds_read_b128 fragment read tiles a contiguous 1KB (conflict-free);
// gload dests are linear (rule #21: chunk permutation applied on the global
// source side).
#define BM 256
#define BN 256
#define BK 64

#define STAGE_A(MH, TS, SD)                                                  \
  GLOAD_LDS16(a_base + (size_t)((MH) * 64) * lda + (TS) * 64,                \
              aL + (SD) * 16384 + (MH) * 8192);                              \
  GLOAD_LDS16(a_base + (size_t)((MH) * 64 + 128) * lda + (TS) * 64,          \
              aL + (SD) * 16384 + (MH) * 8192 + 4096);

#define STAGE_B(NH, TS, SD)                                                  \
  GLOAD_LDS16(b_base + (size_t)((NH) * 32) * K + (TS) * 64,                  \
              bL + (SD) * 16384 + (NH) * 8192);                              \
  GLOAD_LDS16(b_base + (size_t)((NH) * 32 + 128) * K + (TS) * 64,            \
              bL + (SD) * 16384 + (NH) * 8192 + 4096);

#define FRAG_A(D, MH)                                                        \
  _Pragma("unroll") for (int fi = 0; fi < 4; fi++)                           \
    _Pragma("unroll") for (int s = 0; s < 2; s++)                            \
      af[fi][s] = *(const bf16x8*)(arp + (D) * 16384 + (MH) * 8192 +         \
                                   s * 2048 + fi * 512);

#define FRAG_B(D, NH, BF)                                                    \
  _Pragma("unroll") for (int fj = 0; fj < 2; fj++)                           \
    _Pragma("unroll") for (int s = 0; s < 2; s++)                            \
      BF[fj][s] = *(const bf16x8*)(brp + (D) * 16384 + (NH) * 8192 +         \
                                   s * 2048 + fj * 512);

#define MFMA16(AI, BF, BJ)                                                   \
  __builtin_amdgcn_s_setprio(1);                                             \
  _Pragma("unroll") for (int fi = 0; fi < 4; fi++)                           \
    _Pragma("unroll") for (int fj = 0; fj < 2; fj++)                         \
      _Pragma("unroll") for (int s = 0; s < 2; s++)                          \
        acc[(AI) + fi][(BJ) + fj] = __builtin_amdgcn_mfma_f32_16x16x32_bf16( \
            af[fi][s], BF[fj][s], acc[(AI) + fi][(BJ) + fj], 0, 0, 0);       \
  __builtin_amdgcn_s_setprio(0);

#define WAIT_VM4 asm volatile("s_waitcnt vmcnt(4)" ::: "memory")
#define BAR asm volatile("s_barrier" ::: "memory")
#define LGKM0                                                                \
  asm volatile("s_waitcnt lgkmcnt(0)" ::: "memory");                         \
  __builtin_amdgcn_sched_barrier(0)

__global__ __launch_bounds__(512, 2) void gemm_bt(
    const u16* __restrict__ A, int lda,
    const u16* __restrict__ Bt, const float* __restrict__ bias,
    float* __restrict__ Cf, u16* __restrict__ Cb, int M, int K) {
  __shared__ __align__(16) u16 As_[2 * 16384];  // 64 KB
  __shared__ __align__(16) u16 Bs_[2 * 16384];  // 64 KB
  int tid = threadIdx.x;
  int w = tid >> 6, lane = tid & 63;
  int wr = w >> 2, wc = w & 3;

  // bijective XCD swizzle (grid = 392 = 8*49); each XCD gets a contiguous
  // mb range (both nb) -> A-panel L2 reuse.
  int nwg = gridDim.x;
  int flat = blockIdx.x;
  int swz = flat;
  if ((nwg & 7) == 0) swz = (flat & 7) * (nwg >> 3) + (flat >> 3);
  int mb = swz >> 1, nb = swz & 1;
  int m0 = mb * BM, n0 = nb * BN;

  // block-wide staging source addressing: thread tid covers dest u16-offset
  // tid*8 within an 8KB chunk-half: s=(w>>2), r=(w&3)*16+(lane>>2), c=(lane&3)*8
  int srow = (w & 3) * 16 + (lane >> 2);
  int scol = (w >> 2) * 32 + (lane & 3) * 8;
  const u16* a_base = A + (size_t)(m0 + srow) * lda + scol;
  int brow = ((srow >> 5) * 64) + (srow & 31);  // B row-group remap
  const u16* b_base = Bt + (size_t)(n0 + brow) * K + scol;
  u16* aL = &As_[w * 512];  // wave-uniform LDS dest base (+lane*16B by HW)
  u16* bL = &Bs_[w * 512];

  // fragment read bases
  int lr16 = lane & 15, lq4 = lane >> 4;
  const u16* arp = &As_[wr * 4096 + lr16 * 32 + lq4 * 8];
  const u16* brp = &Bs_[(wc >> 1) * 4096 + (wc & 1) * 1024 + lr16 * 32 + lq4 * 8];

  f32x4 acc[8][4];
#pragma unroll
  for (int i = 0; i < 8; i++)
#pragma unroll
    for (int j = 0; j < 4; j++) acc[i][j] = (f32x4){0.f, 0.f, 0.f, 0.f};

  // prologue: tile 0 into buf 0, issue order A0,B0,B1,A1 (= steady state)
  STAGE_A(0, 0, 0);
  STAGE_B(0, 0, 0);
  STAGE_B(1, 0, 0);
  STAGE_A(1, 0, 0);

  bf16x8 af[4][2], bf0[2][2], bf1[2][2];
  int NT = K >> 6;  // K/BK: 8 (layers) or 32 (final)
  for (int t = 0; t < NT; ++t) {
    int d = t & 1, sd = d ^ 1;
    int ts = (t + 1 < NT) ? t + 1 : t;  // clamp: last iter re-stages (unread)
    // P0 (mh=0, nh=0): needs A0,B0 of tile t = oldest 4 of 8 outstanding
    WAIT_VM4;
    BAR;
    FRAG_A(d, 0);
    FRAG_B(d, 0, bf0);
    STAGE_A(0, ts, sd);
    LGKM0;
    MFMA16(0, bf0, 0);
    // P1 (mh=0, nh=1): needs B1 of tile t = oldest 2 of 6
    WAIT_VM4;
    BAR;
    FRAG_B(d, 1, bf1);
    STAGE_B(0, ts, sd);
    LGKM0;
    MFMA16(0, bf1, 2);
    // P2 (mh=1, nh=0): needs A1 of tile t = oldest 2 of 6
    WAIT_VM4;
    BAR;
    FRAG_A(d, 1);
    STAGE_B(1, ts, sd);
    LGKM0;
    MFMA16(4, bf0, 0);
    // P3 (mh=1, nh=1): all operands in regs; no wait, no barrier needed
    STAGE_A(1, ts, sd);
    MFMA16(4, bf1, 2);
  }
  asm volatile("s_waitcnt vmcnt(0)" ::: "memory");  // drain dangling prefetch

  // epilogue: D[row][col], col = lane&15, row = (lane>>4)*4 + reg
#pragma unroll
  for (int i = 0; i < 8; i++) {
    int row_b = m0 + wr * 128 + i * 16 + lq4 * 4;
#pragma unroll
    for (int j = 0; j < 4; j++) {
      int col = n0 + wc * 64 + j * 16 + lr16;
      if (Cf) {
        float bv = bias ? bias[col] : 0.f;
#pragma unroll
        for (int r2 = 0; r2 < 4; r2++) {
          int row = row_b + r2;
          if (row < M) Cf[(size_t)row * DIM + col] = acc[i][j][r2] + bv;
        }
      } else {
        // bf16 scratch has MPAD rows: no bound check needed
#pragma unroll
        for (int r2 = 0; r2 < 4; r2++)
          Cb[(size_t)(row_b + r2) * DIM + col] = f2bf(acc[i][j][r2]);
      }
    }
  }
}

// ---------------- aggregation: one wave per node, 16B/lane, 4-deep edge pipeline
__device__ __forceinline__ void accum8(float* a, uint4 h, float w) {
  a[0] += w * bf2f((u16)(h.x & 0xffffu));
  a[1] += w * bf2f((u16)(h.x >> 16));
  a[2] += w * bf2f((u16)(h.y & 0xffffu));
  a[3] += w * bf2f((u16)(h.y >> 16));
  a[4] += w * bf2f((u16)(h.z & 0xffffu));
  a[5] += w * bf2f((u16)(h.z >> 16));
  a[6] += w * bf2f((u16)(h.w & 0xffffu));
  a[7] += w * bf2f((u16)(h.w >> 16));
}

// reads hp [*,DIM] dense; writes GELU(agg)+bias into xcat column slice (stride INNER)
__global__ __launch_bounds__(256) void k_aggregate(
    const u16* __restrict__ hp, const int* __restrict__ offs,
    const int* __restrict__ csr_src, const float* __restrict__ csr_norm,
    const float* __restrict__ dinv, const float* __restrict__ b,
    u16* __restrict__ out_slice) {
  int v = blockIdx.x * 4 + (threadIdx.x >> 6);
  if (v >= N_NODES) return;
  int lane = threadIdx.x & 63;
  int c8 = lane * 8;  // 8 bf16 = 16 B per lane; wave covers the full 1KB row
  float acc[8];
#pragma unroll
  for (int i = 0; i < 8; i++) acc[i] = 0.f;

  int e0 = offs[v], e1 = offs[v + 1];
  int e = e0;
  for (; e + 4 <= e1; e += 4) {
    int s0 = csr_src[e], s1 = csr_src[e + 1], s2 = csr_src[e + 2], s3 = csr_src[e + 3];
    float w0 = csr_norm[e], w1 = csr_norm[e + 1], w2 = csr_norm[e + 2], w3 = csr_norm[e + 3];
    uint4 h0 = *(const uint4*)(hp + (size_t)s0 * DIM + c8);
    uint4 h1 = *(const uint4*)(hp + (size_t)s1 * DIM + c8);
    uint4 h2 = *(const uint4*)(hp + (size_t)s2 * DIM + c8);
    uint4 h3 = *(const uint4*)(hp + (size_t)s3 * DIM + c8);
    accum8(acc, h0, w0);
    accum8(acc, h1, w1);
    accum8(acc, h2, w2);
    accum8(acc, h3, w3);
  }
  for (; e < e1; e++) {
    int s = csr_src[e];
    float w = csr_norm[e];
    uint4 hv = *(const uint4*)(hp + (size_t)s * DIM + c8);
    accum8(acc, hv, w);
  }
  float di = dinv[v];
  uint4 hv = *(const uint4*)(hp + (size_t)v * DIM + c8);
  accum8(acc, hv, di * di);
  const float4* bb = (const float4*)(b + c8);
  float4 b0 = bb[0], b1 = bb[1];
  acc[0] += b0.x; acc[1] += b0.y; acc[2] += b0.z; acc[3] += b0.w;
  acc[4] += b1.x; acc[5] += b1.y; acc[6] += b1.z; acc[7] += b1.w;
#pragma unroll
  for (int i = 0; i < 8; i++)
    acc[i] = 0.5f * acc[i] * (1.f + erff(acc[i] * 0.70710678118654752f));
  uint4 o;
  o.x = (u32)f2bf(acc[0]) | ((u32)f2bf(acc[1]) << 16);
  o.y = (u32)f2bf(acc[2]) | ((u32)f2bf(acc[3]) << 16);
  o.z = (u32)f2bf(acc[4]) | ((u32)f2bf(acc[5]) << 16);
  o.w = (u32)f2bf(acc[6]) | ((u32)f2bf(acc[7]) << 16);
  *(uint4*)(out_slice + (size_t)v * INNER + c8) = o;
}

// ---------------- BN stats over xcat [N_NODES, INNER] ----------------
__global__ void k_bn_stats(const u16* __restrict__ xcat,
                           float* __restrict__ sums, float* __restrict__ sumsq,
                           int rows_per) {
  int c = blockIdx.x * 512 + threadIdx.x * 2;  // column pair
  int r0 = blockIdx.y * rows_per;
  int r1 = min(N_NODES, r0 + rows_per);
  float s0 = 0.f, ss0 = 0.f, s1 = 0.f, ss1 = 0.f;
  for (int r = r0; r < r1; r++) {
    u32 u = *(const u32*)(xcat + (size_t)r * INNER + c);
    float x0 = bf2f((u16)(u & 0xffffu));
    float x1 = bf2f((u16)(u >> 16));
    s0 += x0; ss0 += x0 * x0;
    s1 += x1; ss1 += x1 * x1;
  }
  atomicAdd(&sums[c], s0);
  atomicAdd(&sumsq[c], ss0);
  atomicAdd(&sums[c + 1], s1);
  atomicAdd(&sumsq[c + 1], ss1);
}

__global__ void k_bn_finalize(const float* __restrict__ sums, const float* __restrict__ sumsq,
                              const float* __restrict__ gamma, const float* __restrict__ beta,
                              float* __restrict__ scale, float* __restrict__ shift) {
  int c = blockIdx.x * blockDim.x + threadIdx.x;
  if (c >= INNER) return;
  float mean = sums[c] / (float)N_NODES;
  float var = sumsq[c] / (float)N_NODES - mean * mean;
  float rstd = rsqrtf(var + BN_EPS);
  float sc = gamma[c] * rstd;
  scale[c] = sc;
  shift[c] = beta[c] - mean * sc;
}

// biasp (zero-initialized) += sum_k shift[k]*outW[k][:]; block 0 also adds outb
__global__ __launch_bounds__(256) void k_fold_bias(
    const float* __restrict__ outW, const float* __restrict__ shift,
    const float* __restrict__ outb, float* __restrict__ biasp) {
  int r0 = blockIdx.x * 64;  // 32 blocks x 64 rows
  int c = threadIdx.x * 2;
  float s0 = 0.f, s1 = 0.f;
  for (int r = 0; r < 64; r++) {
    int row = r0 + r;
    float sh = shift[row];
    float2 w = *(const float2*)(outW + (size_t)row * DIM + c);
    s0 += sh * w.x;
    s1 += sh * w.y;
  }
  if (blockIdx.x == 0) { s0 += outb[c]; s1 += outb[c + 1]; }
  atomicAdd(&biasp[c], s0);
  atomicAdd(&biasp[c + 1], s1);
}

// ---------------- launch ----------------
extern "C" void kernel_launch(void* const* d_in, const int* in_sizes, int n_in,
                              void* d_out, int out_size, void* d_ws, size_t ws_size,
                              hipStream_t stream) {
  (void)in_sizes; (void)n_in; (void)out_size; (void)ws_size;
  const float* x     = (const float*)d_in[0];
  const int*   ei    = (const int*)d_in[1];
  const float* Ws    = (const float*)d_in[2];
  const float* bs    = (const float*)d_in[3];
  const float* gamma = (const float*)d_in[4];
  const float* beta  = (const float*)d_in[5];
  const float* outW  = (const float*)d_in[6];
  const float* outb  = (const float*)d_in[7];
  float* out = (float*)d_out;
  u16*   hp  = (u16*)d_out;  // bf16 h scratch lives in d_out until the final GEMM

  char* ws = (char*)d_ws;
  size_t off = 0;
  auto alloc = [&](size_t bytes) -> void* {
    void* p = ws + off;
    off = (off + bytes + 255) & ~(size_t)255;
    return p;
  };
  // zeroed region first (single memset)
  int*   deg    = (int*)alloc(N_NODES * 4);
  int*   cursor = (int*)alloc(N_NODES * 4);
  float* sums   = (float*)alloc(INNER * 4);
  float* sumsq  = (float*)alloc(INNER * 4);
  float* biasp  = (float*)alloc(DIM * 4);
  size_t zero_bytes = off;
  float* dinv     = (float*)alloc(N_NODES * 4);
  int*   offs     = (int*)alloc((N_NODES + 1) * 4);
  int*   bsum     = (int*)alloc(64 * 4);
  int*   csr_src  = (int*)alloc(N_EDGES * 4);
  float* csr_norm = (float*)alloc(N_EDGES * 4);
  u16*   xcat = (u16*)alloc((size_t)MPAD * INNER * 2);  // unified concat [MPAD, 2048]
  u16*   WbT  = (u16*)alloc((size_t)DIM * DIM * 2);
  u16*   WpT  = (u16*)alloc((size_t)INNER * DIM * 2);
  float* scale = (float*)alloc(INNER * 4);
  float* shift = (float*)alloc(INNER * 4);

  const int SCAN_BLOCKS = (N_NODES + 1023) / 1024;  // 49

  hipMemsetAsync(d_ws, 0, zero_bytes, stream);
  k_deg<<<(N_EDGES + 255) / 256, 256, 0, stream>>>(ei, deg);
  k_dinv<<<(N_NODES + 255) / 256, 256, 0, stream>>>(deg, dinv);
  k_scan1<<<SCAN_BLOCKS, 1024, 0, stream>>>(deg, bsum, N_NODES);
  k_scan2<<<1, 64, 0, stream>>>(bsum, offs, SCAN_BLOCKS);
  k_scan3<<<SCAN_BLOCKS, 1024, 0, stream>>>(deg, bsum, offs, N_NODES);
  k_fill<<<(N_EDGES + 255) / 256, 256, 0, stream>>>(ei, offs, cursor, dinv, csr_src, csr_norm);
  k_convert<<<((N_NODES * DIM / 4) + 255) / 256, 256, 0, stream>>>(x, xcat, N_NODES * DIM / 4);

  dim3 ggrid((MPAD / BM) * (DIM / BN));  // 196*2 = 392 = 8*49 (XCD-divisible)
  for (int l = 0; l < NLAYER; l++) {
    k_transpose_tiled<<<dim3(DIM / 32, DIM / 32), 256, 0, stream>>>(
        Ws + (size_t)l * DIM * DIM, nullptr, WbT, DIM);
    gemm_bt<<<ggrid, 512, 0, stream>>>(xcat + (size_t)l * DIM, INNER, WbT, nullptr,
                                       nullptr, hp, N_NODES, DIM);
    k_aggregate<<<(N_NODES + 3) / 4, 256, 0, stream>>>(hp, offs, csr_src, csr_norm, dinv,
                                                       bs + (size_t)l * DIM,
                                                       xcat + (size_t)(l + 1) * DIM);
  }
  k_bn_stats<<<dim3(INNER / 512, 125), 256, 0, stream>>>(xcat, sums, sumsq, 400);
  k_bn_finalize<<<INNER / 256, 256, 0, stream>>>(sums, sumsq, gamma, beta, scale, shift);
  k_transpose_tiled<<<dim3(INNER / 32, DIM / 32), 256, 0, stream>>>(outW, scale, WpT, INNER);
  k_fold_bias<<<INNER / 64, 256, 0, stream>>>(outW, shift, outb, biasp);
  gemm_bt<<<ggrid, 512, 0, stream>>>(xcat, INNER, WpT, biasp,
                                     out, nullptr, N_NODES, INNER);
}